// Round 4
// baseline (182.693 us; speedup 1.0000x reference)
//
#include <hip/hip_runtime.h>

// GEM forward: v = x·Wv^T + bv ; e = v·We^T + be ; BN over (B,N) per channel;
// out[b, i*N+j, c] = ehat[b,i,c]  (broadcast over j).
// B=8, N=128, C=256  -> rows = B*N = 1024, out = 8*16384*256 fp32 (134 MB).

#define CCH   256      // channels
#define NROWS 1024     // B*N
#define NJ    128      // broadcast factor (N)
#define RPB   8        // rows per block in the GEMM kernel

__global__ __launch_bounds__(256) void k_gemm2(
    const float* __restrict__ x,
    const float* __restrict__ Wv, const float* __restrict__ bv,
    const float* __restrict__ We, const float* __restrict__ be,
    float* __restrict__ e_out, float* __restrict__ sums)
{
    __shared__ float xs[RPB][CCH];
    __shared__ float vs[RPB][CCH];
    const int t    = threadIdx.x;           // output channel d
    const int row0 = blockIdx.x * RPB;

    // stage RPB x-rows (coalesced)
    #pragma unroll
    for (int i = 0; i < RPB; ++i)
        xs[i][t] = x[(row0 + i) * CCH + t];
    __syncthreads();

    // ---- v = x · Wv^T ----
    float acc[RPB];
    #pragma unroll
    for (int i = 0; i < RPB; ++i) acc[i] = 0.0f;
    {
        const float4* wrow = (const float4*)(Wv + (size_t)t * CCH);
        #pragma unroll 4
        for (int c4 = 0; c4 < CCH / 4; ++c4) {
            float4 w = wrow[c4];
            #pragma unroll
            for (int i = 0; i < RPB; ++i) {
                float4 xv = ((const float4*)xs[i])[c4];   // LDS broadcast
                acc[i] = fmaf(w.x, xv.x, acc[i]);
                acc[i] = fmaf(w.y, xv.y, acc[i]);
                acc[i] = fmaf(w.z, xv.z, acc[i]);
                acc[i] = fmaf(w.w, xv.w, acc[i]);
            }
        }
    }
    const float bvt = bv[t];
    #pragma unroll
    for (int i = 0; i < RPB; ++i) vs[i][t] = acc[i] + bvt;
    __syncthreads();

    // ---- e = v · We^T ----
    #pragma unroll
    for (int i = 0; i < RPB; ++i) acc[i] = 0.0f;
    {
        const float4* wrow = (const float4*)(We + (size_t)t * CCH);
        #pragma unroll 4
        for (int c4 = 0; c4 < CCH / 4; ++c4) {
            float4 w = wrow[c4];
            #pragma unroll
            for (int i = 0; i < RPB; ++i) {
                float4 vv = ((const float4*)vs[i])[c4];
                acc[i] = fmaf(w.x, vv.x, acc[i]);
                acc[i] = fmaf(w.y, vv.y, acc[i]);
                acc[i] = fmaf(w.z, vv.z, acc[i]);
                acc[i] = fmaf(w.w, vv.w, acc[i]);
            }
        }
    }
    const float bet = be[t];
    float s = 0.0f, sq = 0.0f;
    #pragma unroll
    for (int i = 0; i < RPB; ++i) {
        float ev = acc[i] + bet;
        e_out[(size_t)(row0 + i) * CCH + t] = ev;
        s += ev;
        sq = fmaf(ev, ev, sq);
    }
    // fused per-channel reduction: 128 blocks x 1 atomic pair per thread
    atomicAdd(&sums[t], s);
    atomicAdd(&sums[CCH + t], sq);
}

// normalize one e-row, write it NJ times. No LDS on the store path:
// each thread owns one float4 chunk (ch = t&63) in registers; the 4 waves
// cover j-phases, each wave's store is a contiguous 1 KB segment.
__global__ __launch_bounds__(256) void k_bcast(
    const float* __restrict__ e, const float* __restrict__ sums,
    const float* __restrict__ gamma, const float* __restrict__ beta,
    float* __restrict__ out)
{
    const int r  = blockIdx.x;       // 0..NROWS-1  (= b*N + i)
    const int t  = threadIdx.x;
    const int ch = t & 63;           // float4 chunk within the row
    const int jb = t >> 6;           // 0..3, j phase of this wave

    const float4 s4 = ((const float4*)sums)[ch];
    const float4 q4 = ((const float4*)(sums + CCH))[ch];
    const float4 g4 = ((const float4*)gamma)[ch];
    const float4 b4 = ((const float4*)beta)[ch];
    const float4 e4 = ((const float4*)(e + (size_t)r * CCH))[ch];

    const float inv_n = 1.0f / (float)NROWS;
    float4 o4;
    {
        float m, var;
        m = s4.x * inv_n; var = fmaf(-m, m, q4.x * inv_n);
        o4.x = fmaf(e4.x - m, rsqrtf(var + 1e-5f) * g4.x, b4.x);
        m = s4.y * inv_n; var = fmaf(-m, m, q4.y * inv_n);
        o4.y = fmaf(e4.y - m, rsqrtf(var + 1e-5f) * g4.y, b4.y);
        m = s4.z * inv_n; var = fmaf(-m, m, q4.z * inv_n);
        o4.z = fmaf(e4.z - m, rsqrtf(var + 1e-5f) * g4.z, b4.z);
        m = s4.w * inv_n; var = fmaf(-m, m, q4.w * inv_n);
        o4.w = fmaf(e4.w - m, rsqrtf(var + 1e-5f) * g4.w, b4.w);
    }

    float4* o = (float4*)(out + (size_t)r * (NJ * CCH));
    // 128 j-values * 64 chunks = 8192 float4 per row; 32 stores per thread.
    #pragma unroll
    for (int it = 0; it < 32; ++it) {
        o[(size_t)(it * 4 + jb) * 64 + ch] = o4;
    }
}

extern "C" void kernel_launch(void* const* d_in, const int* in_sizes, int n_in,
                              void* d_out, int out_size, void* d_ws, size_t ws_size,
                              hipStream_t stream) {
    const float* x     = (const float*)d_in[0];
    const float* Wv    = (const float*)d_in[1];
    const float* bv    = (const float*)d_in[2];
    const float* We    = (const float*)d_in[3];
    const float* be    = (const float*)d_in[4];
    const float* gamma = (const float*)d_in[5];
    const float* beta  = (const float*)d_in[6];
    float* out = (float*)d_out;

    float* e    = (float*)d_ws;             // NROWS*CCH floats = 1 MB
    float* sums = e + (size_t)NROWS * CCH;  // 2*CCH floats (sum, sumsq)

    hipMemsetAsync(sums, 0, 2 * CCH * sizeof(float), stream);
    k_gemm2<<<NROWS / RPB, 256, 0, stream>>>(x, Wv, bv, We, be, e, sums);
    k_bcast<<<NROWS,       256, 0, stream>>>(e, sums, gamma, beta, out);
}

// Round 6
// 176.348 us; speedup vs baseline: 1.0360x; 1.0360x over previous
//
#include <hip/hip_runtime.h>

// GEM forward: v = x·Wv^T + bv ; e = v·We^T + be ; BN over (B,N) per channel;
// out[b, i*N+j, c] = ehat[b,i,c]  (broadcast over j).
// B=8, N=128, C=256  -> rows = B*N = 1024, out = 8*16384*256 fp32 (134 MB).

#define CCH   256      // channels
#define NROWS 1024     // B*N
#define NJ    128      // broadcast factor (N)
#define RPB   4        // rows per block in the GEMM kernel (was 8: VGPR spill risk)

__global__ __launch_bounds__(256) void k_gemm2(
    const float* __restrict__ x,
    const float* __restrict__ Wv, const float* __restrict__ bv,
    const float* __restrict__ We, const float* __restrict__ be,
    float* __restrict__ e_out, float* __restrict__ sums)
{
    __shared__ float xs[RPB][CCH];
    __shared__ float vs[RPB][CCH];
    const int t    = threadIdx.x;           // output channel d
    const int row0 = blockIdx.x * RPB;

    // stage RPB x-rows (coalesced)
    #pragma unroll
    for (int i = 0; i < RPB; ++i)
        xs[i][t] = x[(row0 + i) * CCH + t];
    __syncthreads();

    // ---- v = x · Wv^T ----
    float acc[RPB];
    #pragma unroll
    for (int i = 0; i < RPB; ++i) acc[i] = 0.0f;
    {
        const float4* wrow = (const float4*)(Wv + (size_t)t * CCH);
        #pragma unroll 2
        for (int c4 = 0; c4 < CCH / 4; ++c4) {
            float4 w = wrow[c4];
            #pragma unroll
            for (int i = 0; i < RPB; ++i) {
                float4 xv = ((const float4*)xs[i])[c4];   // LDS broadcast (wave-uniform addr)
                acc[i] = fmaf(w.x, xv.x, acc[i]);
                acc[i] = fmaf(w.y, xv.y, acc[i]);
                acc[i] = fmaf(w.z, xv.z, acc[i]);
                acc[i] = fmaf(w.w, xv.w, acc[i]);
            }
        }
    }
    const float bvt = bv[t];
    #pragma unroll
    for (int i = 0; i < RPB; ++i) vs[i][t] = acc[i] + bvt;
    __syncthreads();

    // ---- e = v · We^T ----
    #pragma unroll
    for (int i = 0; i < RPB; ++i) acc[i] = 0.0f;
    {
        const float4* wrow = (const float4*)(We + (size_t)t * CCH);
        #pragma unroll 2
        for (int c4 = 0; c4 < CCH / 4; ++c4) {
            float4 w = wrow[c4];
            #pragma unroll
            for (int i = 0; i < RPB; ++i) {
                float4 vv = ((const float4*)vs[i])[c4];
                acc[i] = fmaf(w.x, vv.x, acc[i]);
                acc[i] = fmaf(w.y, vv.y, acc[i]);
                acc[i] = fmaf(w.z, vv.z, acc[i]);
                acc[i] = fmaf(w.w, vv.w, acc[i]);
            }
        }
    }
    const float bet = be[t];
    float s = 0.0f, sq = 0.0f;
    #pragma unroll
    for (int i = 0; i < RPB; ++i) {
        float ev = acc[i] + bet;
        e_out[(size_t)(row0 + i) * CCH + t] = ev;
        s += ev;
        sq = fmaf(ev, ev, sq);
    }
    // fused per-channel reduction: NROWS/RPB blocks x 1 atomic pair per thread
    atomicAdd(&sums[t], s);
    atomicAdd(&sums[CCH + t], sq);
}

// normalize one e-row, write it NJ times. 2 blocks per row (64 j each);
// each thread owns one float4 chunk (ch = t&63) in registers; 4 waves cover
// j-phases; each wave's store is a contiguous 1 KB segment.
__global__ __launch_bounds__(256) void k_bcast(
    const float* __restrict__ e, const float* __restrict__ sums,
    const float* __restrict__ gamma, const float* __restrict__ beta,
    float* __restrict__ out)
{
    const int r     = blockIdx.x >> 1;     // 0..NROWS-1  (= b*N + i)
    const int jhalf = blockIdx.x & 1;      // which 64-j half this block covers
    const int t     = threadIdx.x;
    const int ch    = t & 63;              // float4 chunk within the row
    const int jb    = t >> 6;              // 0..3, j phase of this wave

    const float4 s4 = ((const float4*)sums)[ch];
    const float4 q4 = ((const float4*)(sums + CCH))[ch];
    const float4 g4 = ((const float4*)gamma)[ch];
    const float4 b4 = ((const float4*)beta)[ch];
    const float4 e4 = ((const float4*)(e + (size_t)r * CCH))[ch];

    const float inv_n = 1.0f / (float)NROWS;
    float4 o4;
    {
        float m, var;
        m = s4.x * inv_n; var = fmaf(-m, m, q4.x * inv_n);
        o4.x = fmaf(e4.x - m, rsqrtf(var + 1e-5f) * g4.x, b4.x);
        m = s4.y * inv_n; var = fmaf(-m, m, q4.y * inv_n);
        o4.y = fmaf(e4.y - m, rsqrtf(var + 1e-5f) * g4.y, b4.y);
        m = s4.z * inv_n; var = fmaf(-m, m, q4.z * inv_n);
        o4.z = fmaf(e4.z - m, rsqrtf(var + 1e-5f) * g4.z, b4.z);
        m = s4.w * inv_n; var = fmaf(-m, m, q4.w * inv_n);
        o4.w = fmaf(e4.w - m, rsqrtf(var + 1e-5f) * g4.w, b4.w);
    }

    // row region: 128 j * 64 chunks = 8192 float4; this block covers 4096.
    float4* o = (float4*)(out + (size_t)r * (NJ * CCH)) + (size_t)jhalf * 4096;
    #pragma unroll
    for (int it = 0; it < 16; ++it) {
        o[(size_t)(it * 4 + jb) * 64 + ch] = o4;
    }
}

extern "C" void kernel_launch(void* const* d_in, const int* in_sizes, int n_in,
                              void* d_out, int out_size, void* d_ws, size_t ws_size,
                              hipStream_t stream) {
    const float* x     = (const float*)d_in[0];
    const float* Wv    = (const float*)d_in[1];
    const float* bv    = (const float*)d_in[2];
    const float* We    = (const float*)d_in[3];
    const float* be    = (const float*)d_in[4];
    const float* gamma = (const float*)d_in[5];
    const float* beta  = (const float*)d_in[6];
    float* out = (float*)d_out;

    float* e    = (float*)d_ws;             // NROWS*CCH floats = 1 MB
    float* sums = e + (size_t)NROWS * CCH;  // 2*CCH floats (sum, sumsq)

    hipMemsetAsync(sums, 0, 2 * CCH * sizeof(float), stream);
    k_gemm2<<<NROWS / RPB, 256, 0, stream>>>(x, Wv, bv, We, be, e, sums);
    k_bcast<<<NROWS * 2,   256, 0, stream>>>(e, sums, gamma, beta, out);
}